// Round 5
// baseline (256.273 us; speedup 1.0000x reference)
//
#include <hip/hip_runtime.h>
#include <math.h>

// ---------- constants ----------
// B=4 T=1024 E=768 H=12 HD=64, NUM_BUCKETS=320, MAX_DIST=800
#define TT 1024
#define EE 768
#define HH 12

typedef __attribute__((ext_vector_type(8))) __bf16 bf16x8;
typedef __attribute__((ext_vector_type(4))) float f32x4;

__device__ __forceinline__ unsigned short f2b(float f) {
    unsigned int u = __float_as_uint(f);
    unsigned int r = (u + 0x7fffu + ((u >> 16) & 1u)) >> 16;
    return (unsigned short)r;
}

// async global->LDS, 16 bytes per lane; LDS dst must be wave-uniform base + lane*16
#define GLD16(gsrc, ldst) \
    __builtin_amdgcn_global_load_lds( \
        (const __attribute__((address_space(1))) unsigned int*)(gsrc), \
        (__attribute__((address_space(3))) unsigned int*)(ldst), 16, 0, 0)

// ================= setup: one kernel does =================
// [0,4096)      : hs row m -> hsb bf16, xA (lora down, fp32), gates
// [4096,5248)   : convert Wq|Wk|Wv|Wo fp32 -> bf16 row-major (Wall_b)
// [5248,5356)   : WqT/WkT/WvT bf16 transposed copies (for W2 gemm B-operand)
// [5356,5452)   : biasTab
// [5452,5464)   : bias2 = W@b + b (fp32), B2 = W@Bm (fp32)
__global__ __launch_bounds__(256)
void setup_k(const float* __restrict__ hs,
             const float* __restrict__ Wq, const float* __restrict__ Wk,
             const float* __restrict__ Wv, const float* __restrict__ Wo,
             const float* __restrict__ bq, const float* __restrict__ bk,
             const float* __restrict__ bv,
             const float* __restrict__ Aq, const float* __restrict__ Ak,
             const float* __restrict__ Av,
             const float* __restrict__ Bq, const float* __restrict__ Bk,
             const float* __restrict__ Bv,
             const float* __restrict__ Wg, const float* __restrict__ bg,
             const float* __restrict__ gru, const float* __restrict__ rel,
             unsigned short* __restrict__ hsb, unsigned short* __restrict__ Wall_b,
             unsigned short* __restrict__ WT_all,
             float* __restrict__ xA, float* __restrict__ gate,
             float* __restrict__ biasTab, float* __restrict__ bias2,
             float* __restrict__ B2) {
    __shared__ __align__(16) char smem[34816];
    const int bid = blockIdx.x, tid = threadIdx.x;

    if (bid < 4096) {                       // ---- hs rows ----
        float* rowF = (float*)smem;          // 768
        float* WgS  = rowF + 768;            // 512
        float* bgS  = WgS + 512;             // 8
        float* gpS  = bgS + 8;               // 96
        float* redS = gpS + 96;              // 24
        const int m = bid;
        const float* xrow = hs + (size_t)m * EE;
        if (tid < 192) {
            float4 f = ((const float4*)xrow)[tid];
            rowF[tid * 4 + 0] = f.x; rowF[tid * 4 + 1] = f.y;
            rowF[tid * 4 + 2] = f.z; rowF[tid * 4 + 3] = f.w;
            unsigned int lo = (unsigned int)f2b(f.x) | ((unsigned int)f2b(f.y) << 16);
            unsigned int hi = (unsigned int)f2b(f.z) | ((unsigned int)f2b(f.w) << 16);
            uint2 p; p.x = lo; p.y = hi;
            *(uint2*)&hsb[(size_t)m * EE + tid * 4] = p;
        }
        for (int i = tid; i < 512; i += 256) WgS[i] = Wg[i];
        if (tid < 8) bgS[tid] = bg[tid];
        __syncthreads();
        // lora down partials (3 elems/thread)
        float s[6] = {0.f, 0.f, 0.f, 0.f, 0.f, 0.f};
        #pragma unroll
        for (int j = 0; j < 3; ++j) {
            int e = tid * 3 + j;
            float xv = rowF[e];
            s[0] += xv * Aq[e]; s[1] += xv * Aq[EE + e];
            s[2] += xv * Ak[e]; s[3] += xv * Ak[EE + e];
            s[4] += xv * Av[e]; s[5] += xv * Av[EE + e];
        }
        #pragma unroll
        for (int off = 32; off > 0; off >>= 1)
            #pragma unroll
            for (int i = 0; i < 6; ++i) s[i] += __shfl_down(s[i], off, 64);
        if ((tid & 63) == 0)
            #pragma unroll
            for (int i = 0; i < 6; ++i) redS[(tid >> 6) * 6 + i] = s[i];
        // gates: gp[h][e]
        if (tid < 96) {
            int h = tid >> 3, e = tid & 7;
            float acc = 0.f;
            #pragma unroll 16
            for (int d = 0; d < 64; ++d) acc += rowF[h * 64 + d] * WgS[e * 64 + d];
            gpS[h * 8 + e] = acc + bgS[e];
        }
        __syncthreads();
        if (tid < 6) {
            float v = redS[tid] + redS[6 + tid] + redS[12 + tid] + redS[18 + tid];
            int sel = tid >> 1, r = tid & 1;
            xA[sel * 8192 + m * 2 + r] = v;
        }
        if (tid < 12) {
            int h = tid;
            float s0 = gpS[h * 8 + 0] + gpS[h * 8 + 1] + gpS[h * 8 + 2] + gpS[h * 8 + 3];
            float s1 = gpS[h * 8 + 4] + gpS[h * 8 + 5] + gpS[h * 8 + 6] + gpS[h * 8 + 7];
            float ga = 1.f / (1.f + __expf(-s0));
            float gb = 1.f / (1.f + __expf(-s1));
            int b = m >> 10, tp = m & 1023;
            gate[((size_t)b * HH + h) * TT + tp] = ga * (gb * gru[h] - 1.0f) + 2.0f;
        }
    } else if (bid < 5248) {                // ---- weight convert ----
        size_t base = (size_t)(bid - 4096) * 2048 + tid * 8;
        int mat = (int)(base / 589824);
        size_t local = base % 589824;
        const float* S = mat == 0 ? Wq : (mat == 1 ? Wk : (mat == 2 ? Wv : Wo));
        float4 a = *(const float4*)&S[local];
        float4 c = *(const float4*)&S[local + 4];
        unsigned short hb[8] __attribute__((aligned(16)));
        hb[0] = f2b(a.x); hb[1] = f2b(a.y); hb[2] = f2b(a.z); hb[3] = f2b(a.w);
        hb[4] = f2b(c.x); hb[5] = f2b(c.y); hb[6] = f2b(c.z); hb[7] = f2b(c.w);
        *(uint4*)&Wall_b[base] = *(const uint4*)hb;
    } else if (bid < 5356) {                // ---- W transpose (bf16) ----
        unsigned short* Ts = (unsigned short*)smem;   // [128][136]
        int v = bid - 5248;
        int mat = v / 36, tile = v % 36;
        int tr = tile / 6, tc = tile % 6;
        const float* S = mat == 0 ? Wq : (mat == 1 ? Wk : Wv);
        #pragma unroll
        for (int i = 0; i < 16; ++i) {
            int idx = i * 256 + tid;
            int row = idx >> 5, col4 = (idx & 31) * 4;
            float4 f = *(const float4*)&S[(size_t)(tr * 128 + row) * EE + tc * 128 + col4];
            Ts[(col4 + 0) * 136 + row] = f2b(f.x);
            Ts[(col4 + 1) * 136 + row] = f2b(f.y);
            Ts[(col4 + 2) * 136 + row] = f2b(f.z);
            Ts[(col4 + 3) * 136 + row] = f2b(f.w);
        }
        __syncthreads();
        unsigned short* dst = WT_all + (size_t)mat * 589824;
        #pragma unroll
        for (int i = 0; i < 8; ++i) {
            int idx = i * 256 + tid;
            int rr = idx >> 4, cg = (idx & 15) * 8;
            *(uint4*)&dst[(size_t)(tc * 128 + rr) * EE + tr * 128 + cg] =
                *(const uint4*)&Ts[rr * 136 + cg];
        }
    } else if (bid < 5452) {                // ---- biasTab ----
        int idx = (bid - 5356) * 256 + tid;
        if (idx < 2047 * 12) {
            int h = idx % 12;
            int rr = idx / 12;
            int relv = rr - 1023;
            int base = relv > 0 ? 160 : 0;
            int ar = relv < 0 ? -relv : relv;
            int bkt;
            if (ar < 80) bkt = base + ar;
            else {
                double lr = log((double)ar / 80.0);
                int large = 80 + (int)(lr / log(10.0) * 80.0);
                if (large > 159) large = 159;
                bkt = base + large;
            }
            biasTab[h * 2048 + rr] = rel[bkt * 12 + h];
        }
    } else {                                // ---- bias2 / B2 ----
        float* bvS = (float*)smem;           // 768
        float* BmS = bvS + 768;              // 1536
        int v = bid - 5452;                  // 0..11
        int sel = v / 4, nb = (v % 4) * 192;
        const float* W = sel == 0 ? Wq : (sel == 1 ? Wk : Wv);
        const float* bvec = sel == 0 ? bq : (sel == 1 ? bk : bv);
        const float* Bm = sel == 0 ? Bq : (sel == 1 ? Bk : Bv);
        for (int i = tid; i < 768; i += 256) bvS[i] = bvec[i];
        for (int i = tid; i < 1536; i += 256) BmS[i] = Bm[i];
        __syncthreads();
        if (tid < 192) {
            int n = nb + tid;
            const float* Wrow = W + (size_t)n * EE;
            float a0 = 0.f, a1 = 0.f, a2 = 0.f;
            for (int o = 0; o < EE; o += 4) {
                float4 w = *(const float4*)&Wrow[o];
                a0 += w.x * bvS[o] + w.y * bvS[o + 1] + w.z * bvS[o + 2] + w.w * bvS[o + 3];
                a1 += w.x * BmS[o * 2] + w.y * BmS[o * 2 + 2] + w.z * BmS[o * 2 + 4] + w.w * BmS[o * 2 + 6];
                a2 += w.x * BmS[o * 2 + 1] + w.y * BmS[o * 2 + 3] + w.z * BmS[o * 2 + 5] + w.w * BmS[o * 2 + 7];
            }
            bias2[sel * 768 + n] = a0 + bvS[n];
            B2[sel * 1536 + n * 2 + 0] = a1;
            B2[sel * 1536 + n * 2 + 1] = a2;
        }
    }
}

// ---------- W2 = W@W (bf16), 108 blocks of 128x128 ----------
__global__ __launch_bounds__(256, 2)
void wgemm_k(const unsigned short* __restrict__ Wall_b,
             const unsigned short* __restrict__ WT_all,
             unsigned short* __restrict__ W2_all) {
    __shared__ unsigned short At[128 * 32];
    __shared__ unsigned short Bt[128 * 32];
    const int tid = threadIdx.x;
    const int bxx = blockIdx.x;
    const int sel = bxx / 36, tile = bxx % 36;
    const int row0 = (tile / 6) * 128, col0 = (tile % 6) * 128;
    const unsigned short* A = Wall_b + (size_t)sel * 589824;
    const unsigned short* Bw = WT_all + (size_t)sel * 589824;

    const int lane = tid & 63, wv = tid >> 6;
    const int wm = (wv & 1) * 64, wn = (wv >> 1) * 64;
    const int l15 = lane & 15, g8 = (lane >> 4) * 8;
    const int lr = lane >> 2, lc = (lane & 3) * 8;
    const int c0 = wv * 2, c1 = wv * 2 + 1;
    const unsigned short* Abase0 = A + (size_t)(row0 + c0 * 16 + lr) * EE + lc;
    const unsigned short* Abase1 = A + (size_t)(row0 + c1 * 16 + lr) * EE + lc;
    const unsigned short* Bbase0 = Bw + (size_t)(col0 + c0 * 16 + lr) * EE + lc;
    const unsigned short* Bbase1 = Bw + (size_t)(col0 + c1 * 16 + lr) * EE + lc;

    f32x4 zero4 = {0.f, 0.f, 0.f, 0.f};
    f32x4 acc[4][4];
    #pragma unroll
    for (int i = 0; i < 4; ++i)
        #pragma unroll
        for (int j = 0; j < 4; ++j) acc[i][j] = zero4;

    for (int kt = 0; kt < 768; kt += 32) {
        GLD16(Abase0 + kt, &At[c0 * 512]);
        GLD16(Abase1 + kt, &At[c1 * 512]);
        GLD16(Bbase0 + kt, &Bt[c0 * 512]);
        GLD16(Bbase1 + kt, &Bt[c1 * 512]);
        __syncthreads();
        bf16x8 af[4], bf[4];
        #pragma unroll
        for (int mt = 0; mt < 4; ++mt) af[mt] = *(const bf16x8*)&At[(wm + mt * 16 + l15) * 32 + g8];
        #pragma unroll
        for (int nt = 0; nt < 4; ++nt) bf[nt] = *(const bf16x8*)&Bt[(wn + nt * 16 + l15) * 32 + g8];
        #pragma unroll
        for (int mt = 0; mt < 4; ++mt)
            #pragma unroll
            for (int nt = 0; nt < 4; ++nt)
                acc[mt][nt] = __builtin_amdgcn_mfma_f32_16x16x32_bf16(af[mt], bf[nt], acc[mt][nt], 0, 0, 0);
        __syncthreads();
    }
    unsigned short* out = W2_all + (size_t)sel * 589824;
    const int g4 = (lane >> 4) * 4;
    #pragma unroll
    for (int mt = 0; mt < 4; ++mt)
        #pragma unroll
        for (int r = 0; r < 4; ++r) {
            int grow = row0 + wm + mt * 16 + g4 + r;
            #pragma unroll
            for (int nt = 0; nt < 4; ++nt) {
                int ncol = col0 + wn + nt * 16 + l15;
                out[(size_t)grow * EE + ncol] = f2b(acc[mt][nt][r]);
            }
        }
}

// ---------- fused QKV GEMM (MODE 0) and output GEMM (MODE 2) ----------
// MODE 0: A=hsb, W=W2_all, grid(18,32), sel=bx/6; out: q->qb, k->kb, v->Vtg (transposed)
// MODE 2: A=ctxb, W=Wob, grid(6,32), out=d_out fp32 (+bo)
template<int MODE>
__global__ __launch_bounds__(256, 2)
void gemm_k(const unsigned short* __restrict__ Aall,
            const unsigned short* __restrict__ Wb_base,
            const float* __restrict__ bias_base,
            const float* __restrict__ xA, const float* __restrict__ B2,
            unsigned short* __restrict__ qb, unsigned short* __restrict__ kb,
            unsigned short* __restrict__ Vtg, float* __restrict__ outf) {
    __shared__ unsigned short At[128 * 32];
    __shared__ unsigned short Bt[128 * 32];
    const int tid = threadIdx.x;
    const int bx = blockIdx.x, by = blockIdx.y;
    int sel, row0, col0;
    if (MODE == 0) { sel = bx / 6; col0 = (bx % 6) * 128; row0 = by * 128; }
    else           { sel = 0;      col0 = bx * 128;       row0 = by * 128; }
    const unsigned short* Wb = Wb_base + (size_t)sel * 589824;
    const float* bias = bias_base + sel * 768;
    const float scale = (MODE == 0 && sel == 0) ? 0.125f : 1.0f;

    const int lane = tid & 63, wv = tid >> 6;
    const int wm = (wv & 1) * 64, wn = (wv >> 1) * 64;
    const int l15 = lane & 15, g8 = (lane >> 4) * 8;
    const int lr = lane >> 2, lc = (lane & 3) * 8;
    const int c0 = wv * 2, c1 = wv * 2 + 1;
    const unsigned short* Abase0 = Aall + (size_t)(row0 + c0 * 16 + lr) * EE + lc;
    const unsigned short* Abase1 = Aall + (size_t)(row0 + c1 * 16 + lr) * EE + lc;
    const unsigned short* Bbase0 = Wb + (size_t)(col0 + c0 * 16 + lr) * EE + lc;
    const unsigned short* Bbase1 = Wb + (size_t)(col0 + c1 * 16 + lr) * EE + lc;

    f32x4 zero4 = {0.f, 0.f, 0.f, 0.f};
    f32x4 acc[4][4];
    #pragma unroll
    for (int i = 0; i < 4; ++i)
        #pragma unroll
        for (int j = 0; j < 4; ++j) acc[i][j] = zero4;

    for (int kt = 0; kt < 768; kt += 32) {
        GLD16(Abase0 + kt, &At[c0 * 512]);
        GLD16(Abase1 + kt, &At[c1 * 512]);
        GLD16(Bbase0 + kt, &Bt[c0 * 512]);
        GLD16(Bbase1 + kt, &Bt[c1 * 512]);
        __syncthreads();
        bf16x8 af[4], bf[4];
        #pragma unroll
        for (int mt = 0; mt < 4; ++mt) af[mt] = *(const bf16x8*)&At[(wm + mt * 16 + l15) * 32 + g8];
        #pragma unroll
        for (int nt = 0; nt < 4; ++nt) bf[nt] = *(const bf16x8*)&Bt[(wn + nt * 16 + l15) * 32 + g8];
        #pragma unroll
        for (int mt = 0; mt < 4; ++mt)
            #pragma unroll
            for (int nt = 0; nt < 4; ++nt)
                acc[mt][nt] = __builtin_amdgcn_mfma_f32_16x16x32_bf16(af[mt], bf[nt], acc[mt][nt], 0, 0, 0);
        __syncthreads();
    }

    const float* Lbase = (MODE == 0) ? (xA + sel * 8192) : nullptr;
    const float* B2s   = (MODE == 0) ? (B2 + sel * 1536) : nullptr;
    const int g4 = (lane >> 4) * 4;
    #pragma unroll
    for (int mt = 0; mt < 4; ++mt) {
        #pragma unroll
        for (int r = 0; r < 4; ++r) {
            size_t grow = (size_t)row0 + wm + mt * 16 + g4 + r;
            float l0 = 0.f, l1 = 0.f;
            if (MODE == 0) { l0 = Lbase[grow * 2]; l1 = Lbase[grow * 2 + 1]; }
            #pragma unroll
            for (int nt = 0; nt < 4; ++nt) {
                int ncol = col0 + wn + nt * 16 + l15;
                float c = acc[mt][nt][r] + bias[ncol];
                if (MODE == 0) {
                    c = (c + 0.5f * (l0 * B2s[ncol * 2] + l1 * B2s[ncol * 2 + 1])) * scale;
                    if (sel == 0)      qb[grow * EE + ncol] = f2b(c);
                    else if (sel == 1) kb[grow * EE + ncol] = f2b(c);
                    else {
                        int b = (int)(grow >> 10), t = (int)(grow & 1023);
                        int h = ncol >> 6, d = ncol & 63;
                        Vtg[(((size_t)b * HH + h) * 64 + d) * TT + t] = f2b(c);
                    }
                } else {
                    outf[grow * EE + ncol] = c;
                }
            }
        }
    }
}

// ---------- MFMA flash attention (no-max softmax; scores bounded) ----------
__global__ __launch_bounds__(256, 3)
void attn_k(const unsigned short* __restrict__ qb, const unsigned short* __restrict__ kb,
            const unsigned short* __restrict__ Vtg, const float* __restrict__ gate,
            const float* __restrict__ biasTab, unsigned short* __restrict__ ctx) {
    __shared__ unsigned short Qs[64 * 72];   // [m][d]
    __shared__ unsigned short Ks[64 * 72];   // [key][d]  (reused as O at end)
    __shared__ unsigned short Vt[64 * 72];   // [d][key]
    __shared__ unsigned short Ps[64 * 72];   // [m][key]
    __shared__ float btabS[2048];
    const int tid = threadIdx.x;
    const int qt = blockIdx.x, h = blockIdx.y, b = blockIdx.z;

    for (int i = tid; i < 2047; i += 256) btabS[i] = biasTab[h * 2048 + i];

    const int srow = tid >> 2, scol = (tid & 3) * 16;
    {
        const unsigned short* qp = qb + ((size_t)(b * TT + qt * 64 + srow)) * EE + h * 64 + scol;
        *(uint4*)&Qs[srow * 72 + scol]     = *(const uint4*)qp;
        *(uint4*)&Qs[srow * 72 + scol + 8] = *(const uint4*)(qp + 8);
    }
    const int lane = tid & 63, wv = tid >> 6;
    const int m0 = wv * 16;
    const int l15 = lane & 15, g = lane >> 4;

    float li[4];
    f32x4 zero4 = {0.f, 0.f, 0.f, 0.f};
    f32x4 oa[4];
    #pragma unroll
    for (int r = 0; r < 4; ++r) li[r] = 0.f;
    #pragma unroll
    for (int nt = 0; nt < 4; ++nt) oa[nt] = zero4;
    float gv[4];
    #pragma unroll
    for (int r = 0; r < 4; ++r)
        gv[r] = gate[((size_t)(b * HH + h)) * TT + qt * 64 + m0 + 4 * g + r];
    const unsigned short* vrow = Vtg + ((size_t)(b * HH + h) * 64 + srow) * TT;
    __syncthreads();

    for (int kt = 0; kt < 16; ++kt) {
        {
            const unsigned short* kp = kb + ((size_t)(b * TT + kt * 64 + srow)) * EE + h * 64 + scol;
            *(uint4*)&Ks[srow * 72 + scol]     = *(const uint4*)kp;
            *(uint4*)&Ks[srow * 72 + scol + 8] = *(const uint4*)(kp + 8);
            const unsigned short* vp = vrow + kt * 64 + scol;
            *(uint4*)&Vt[srow * 72 + scol]     = *(const uint4*)vp;
            *(uint4*)&Vt[srow * 72 + scol + 8] = *(const uint4*)(vp + 8);
        }
        __syncthreads();
        f32x4 sa[4];
        #pragma unroll
        for (int nt = 0; nt < 4; ++nt) sa[nt] = zero4;
        bf16x8 aq0 = *(const bf16x8*)&Qs[(m0 + l15) * 72 + g * 8];
        bf16x8 aq1 = *(const bf16x8*)&Qs[(m0 + l15) * 72 + 32 + g * 8];
        #pragma unroll
        for (int nt = 0; nt < 4; ++nt) {
            bf16x8 bk0 = *(const bf16x8*)&Ks[(nt * 16 + l15) * 72 + g * 8];
            bf16x8 bk1 = *(const bf16x8*)&Ks[(nt * 16 + l15) * 72 + 32 + g * 8];
            sa[nt] = __builtin_amdgcn_mfma_f32_16x16x32_bf16(aq0, bk0, sa[nt], 0, 0, 0);
            sa[nt] = __builtin_amdgcn_mfma_f32_16x16x32_bf16(aq1, bk1, sa[nt], 0, 0, 0);
        }
        #pragma unroll
        for (int nt = 0; nt < 4; ++nt) {
            int ibase = kt * 64 + nt * 16 + l15 + 1023 - qt * 64 - m0 - 4 * g;
            #pragma unroll
            for (int r = 0; r < 4; ++r) {
                float e = __expf(sa[nt][r] + gv[r] * btabS[ibase - r]);
                li[r] += e;
                Ps[(m0 + 4 * g + r) * 72 + nt * 16 + l15] = f2b(e);
            }
        }
        bf16x8 ap0 = *(const bf16x8*)&Ps[(m0 + l15) * 72 + g * 8];
        bf16x8 ap1 = *(const bf16x8*)&Ps[(m0 + l15) * 72 + 32 + g * 8];
        #pragma unroll
        for (int nt = 0; nt < 4; ++nt) {
            bf16x8 bv0 = *(const bf16x8*)&Vt[(nt * 16 + l15) * 72 + g * 8];
            bf16x8 bv1 = *(const bf16x8*)&Vt[(nt * 16 + l15) * 72 + 32 + g * 8];
            oa[nt] = __builtin_amdgcn_mfma_f32_16x16x32_bf16(ap0, bv0, oa[nt], 0, 0, 0);
            oa[nt] = __builtin_amdgcn_mfma_f32_16x16x32_bf16(ap1, bv1, oa[nt], 0, 0, 0);
        }
        __syncthreads();
    }
    #pragma unroll
    for (int r = 0; r < 4; ++r) {
        #pragma unroll
        for (int msk = 1; msk < 16; msk <<= 1)
            li[r] += __shfl_xor(li[r], msk, 16);
    }
    #pragma unroll
    for (int nt = 0; nt < 4; ++nt)
        #pragma unroll
        for (int r = 0; r < 4; ++r)
            Ks[(m0 + 4 * g + r) * 72 + nt * 16 + l15] = f2b(oa[nt][r] / li[r]);
    __syncthreads();
    {
        unsigned short* cp = ctx + ((size_t)(b * TT + qt * 64 + srow)) * EE + h * 64 + scol;
        *(uint4*)cp       = *(const uint4*)&Ks[srow * 72 + scol];
        *(uint4*)(cp + 8) = *(const uint4*)&Ks[srow * 72 + scol + 8];
    }
}

// ---------- launch ----------
extern "C" void kernel_launch(void* const* d_in, const int* in_sizes, int n_in,
                              void* d_out, int out_size, void* d_ws, size_t ws_size,
                              hipStream_t stream) {
    const float* hs  = (const float*)d_in[0];
    const float* Wq  = (const float*)d_in[1];
    const float* bq  = (const float*)d_in[2];
    const float* Wk  = (const float*)d_in[3];
    const float* bk  = (const float*)d_in[4];
    const float* Wv  = (const float*)d_in[5];
    const float* bv  = (const float*)d_in[6];
    const float* Aq  = (const float*)d_in[7];
    const float* Bq  = (const float*)d_in[8];
    const float* Ak  = (const float*)d_in[9];
    const float* Bk  = (const float*)d_in[10];
    const float* Av  = (const float*)d_in[11];
    const float* Bv  = (const float*)d_in[12];
    const float* Wo  = (const float*)d_in[13];
    const float* bo  = (const float*)d_in[14];
    const float* Wg  = (const float*)d_in[15];
    const float* bg  = (const float*)d_in[16];
    const float* gru = (const float*)d_in[17];
    const float* rel = (const float*)d_in[18];

    float* ws = (float*)d_ws;
    float* gate    = ws;                    // 49152
    float* biasTab = gate + 49152;          // 24576
    float* xA      = biasTab + 24576;       // 24576
    float* bias2   = xA + 24576;            // 2304
    float* B2      = bias2 + 2304;          // 4608
    unsigned short* hsb    = (unsigned short*)(B2 + 4608);
    unsigned short* Wall_b = hsb + 3145728;          // 4 x 589824 (Wq,Wk,Wv,Wo)
    unsigned short* WT_all = Wall_b + 4 * 589824;    // 3 x 589824
    unsigned short* W2_all = WT_all + 3 * 589824;    // 3 x 589824
    unsigned short* qb     = W2_all + 3 * 589824;
    unsigned short* kb     = qb + 3145728;
    unsigned short* Vtg    = kb + 3145728;
    unsigned short* ctxb   = Vtg + 3145728;

    setup_k<<<5464, 256, 0, stream>>>(hs, Wq, Wk, Wv, Wo, bq, bk, bv,
                                      Aq, Ak, Av, Bq, Bk, Bv, Wg, bg, gru, rel,
                                      hsb, Wall_b, WT_all, xA, gate, biasTab, bias2, B2);
    wgemm_k<<<108, 256, 0, stream>>>(Wall_b, WT_all, W2_all);
    gemm_k<0><<<dim3(18, 32), 256, 0, stream>>>(hsb, W2_all, bias2, xA, B2,
                                                qb, kb, Vtg, nullptr);
    attn_k<<<dim3(16, 12, 4), 256, 0, stream>>>(qb, kb, Vtg, gate, biasTab, ctxb);
    gemm_k<2><<<dim3(6, 32), 256, 0, stream>>>(ctxb, Wall_b + 3 * 589824, bo,
                                               nullptr, nullptr, nullptr, nullptr, nullptr,
                                               (float*)d_out);
}